// Round 2
// baseline (214.036 us; speedup 1.0000x reference)
//
#include <hip/hip_runtime.h>
#include <cstdint>

// Problem constants: N=8192, T=1024, CD=4, H=2, KD=VD=8, DA=8, AOD=16, LAT=64, OUT=32.

__device__ __forceinline__ float bflo(uint32_t u) { return __uint_as_float(u << 16); }
__device__ __forceinline__ float bfhi(uint32_t u) { return __uint_as_float(u & 0xFFFF0000u); }
__device__ __forceinline__ uint32_t f2bf(float f) {
    uint32_t x = __float_as_uint(f);
    return (x + 0x7FFFu + ((x >> 16) & 1u)) >> 16;   // RNE
}
__device__ __forceinline__ float ftanh(float x) {
    float e = __expf(2.0f * x);
    return 1.0f - 2.0f / (e + 1.0f);   // stable for +-inf of e
}

__global__ __launch_bounds__(256, 5)
void attn_mlp_fused(const float* __restrict__ coord1,
                    const float* __restrict__ coord2,
                    const float* __restrict__ att_coeff,
                    const float* __restrict__ local_coords,
                    const void*  __restrict__ maskp,
                    const float* __restrict__ Wq, const float* __restrict__ Bq,
                    const float* __restrict__ Wk, const float* __restrict__ Bk,
                    const float* __restrict__ Wv, const float* __restrict__ Bv,
                    const float* __restrict__ Wo, const float* __restrict__ Bo,
                    const float* __restrict__ W1, const float* __restrict__ B1,
                    const float* __restrict__ W2, const float* __restrict__ B2,
                    const float* __restrict__ Wt, const float* __restrict__ Bt,
                    float* __restrict__ out)
{
    __shared__ uint4 vq[2048];                 // v table, bf16x2 packed, swizzled (exactly 32 KB)

    const int tid  = threadIdx.x;
    const int lane = tid & 63;
    const int wid  = tid >> 6;

    // ---- detect mask element size: 4-byte (int/float 0/1) vs 1-byte (bool) ----
    uint4 mm = ((const uint4*)maskp)[tid];
    bool ok = (mm.x <= 1u || mm.x == 0x3F800000u) &&
              (mm.y <= 1u || mm.y == 0x3F800000u) &&
              (mm.z <= 1u || mm.z == 0x3F800000u) &&
              (mm.w <= 1u || mm.w == 0x3F800000u);
    const bool m4 = (__all(ok) != 0);

    // ---- stage v = att_coeff @ Wv + Bv into LDS (bf16x2, XOR-swizzled) ----
    #pragma unroll
    for (int tt = 0; tt < 4; ++tt) {
        const int t = tid * 4 + tt;
        const float4 a0 = *(const float4*)(att_coeff + t * 8);
        const float4 a1 = *(const float4*)(att_coeff + t * 8 + 4);
        float vr[16];
        #pragma unroll
        for (int o = 0; o < 16; ++o) {
            vr[o] = Bv[o]
                + a0.x * Wv[o]      + a0.y * Wv[16 + o] + a0.z * Wv[32 + o] + a0.w * Wv[48 + o]
                + a1.x * Wv[64 + o] + a1.y * Wv[80 + o] + a1.z * Wv[96 + o] + a1.w * Wv[112 + o];
        }
        #pragma unroll
        for (int h = 0; h < 2; ++h) {
            const int g  = 2 * t + h;
            const int gs = (g & ~7) | ((g ^ (g >> 3)) & 7);
            uint4 pk;
            pk.x = f2bf(vr[h * 8 + 0]) | (f2bf(vr[h * 8 + 1]) << 16);
            pk.y = f2bf(vr[h * 8 + 2]) | (f2bf(vr[h * 8 + 3]) << 16);
            pk.z = f2bf(vr[h * 8 + 4]) | (f2bf(vr[h * 8 + 5]) << 16);
            pk.w = f2bf(vr[h * 8 + 6]) | (f2bf(vr[h * 8 + 7]) << 16);
            vq[gs] = pk;
        }
    }
    __syncthreads();

    const int  l2  = (lane >> 2) & 7;
    const int  bg0 = ((2 * lane)     & ~7) | (((2 * lane)     ^ l2) & 7);
    const int  bg1 = ((2 * lane + 1) & ~7) | (((2 * lane + 1) ^ l2) & 7);
    const float rs8 = 0.35355339059327373f;   // 1/sqrt(KD)

    const uint32_t msh   = m4 ? 0u : ((lane & 3) * 8);
    const uint32_t mmsk  = m4 ? 0xFFFFFFFFu : 0xFFu;
    const int      mstep = m4 ? 64 : 16;

    #pragma unroll
    for (int it = 0; it < 2; ++it) {
        const int n = (blockIdx.x << 3) + (it << 2) + wid;

        const float4 c1 = *(const float4*)(coord1 + n * 4);
        const float4 c2 = *(const float4*)(coord2 + n * 4);

        float q[16];
        #pragma unroll
        for (int o = 0; o < 16; ++o)
            q[o] = Bq[o] + c1.x * Wq[o] + c1.y * Wq[16 + o] + c1.z * Wq[32 + o] + c1.w * Wq[48 + o];

        float A[2][4], Bs[2];
        #pragma unroll
        for (int h = 0; h < 2; ++h) {
            #pragma unroll
            for (int c = 0; c < 4; ++c) {
                float s = 0.f;
                #pragma unroll
                for (int d = 0; d < 8; ++d) s += q[h * 8 + d] * Wk[c * 16 + h * 8 + d];
                A[h][c] = s * rs8;
            }
            float s2 = 0.f;
            #pragma unroll
            for (int d = 0; d < 8; ++d) s2 += q[h * 8 + d] * Bk[h * 8 + d];
            Bs[h] = s2 * rs8;
        }

        // ---- online softmax + PV in ONE pass over T (t = i*64 + lane) ----
        const float4*   lcp = (const float4*)local_coords + (size_t)n * 1024 + lane;
        const uint32_t* mp  = (const uint32_t*)maskp +
                              (m4 ? ((size_t)n * 1024 + lane)
                                  : ((size_t)n * 256 + (lane >> 2)));

        float p[16];
        #pragma unroll
        for (int k = 0; k < 16; ++k) p[k] = 0.f;
        float m0 = -1e30f, m1 = -1e30f, s0 = 0.f, s1 = 0.f;

        #pragma unroll
        for (int i = 0; i < 16; ++i) {
            const float4   lc = lcp[i * 64];
            const uint32_t mw = mp[i * mstep];
            const bool keep = ((mw >> msh) & mmsk) != 0u;

            float v0 = Bs[0] + lc.x * A[0][0] + lc.y * A[0][1] + lc.z * A[0][2] + lc.w * A[0][3];
            float v1 = Bs[1] + lc.x * A[1][0] + lc.y * A[1][1] + lc.z * A[1][2] + lc.w * A[1][3];
            v0 = keep ? v0 : -1e30f;
            v1 = keep ? v1 : -1e30f;

            const float m0n = fmaxf(m0, v0);
            const float m1n = fmaxf(m1, v1);
            const float sc0 = __expf(m0 - m0n);
            const float sc1 = __expf(m1 - m1n);
            const float e0  = keep ? __expf(v0 - m0n) : 0.0f;
            const float e1  = keep ? __expf(v1 - m1n) : 0.0f;
            m0 = m0n; m1 = m1n;
            s0 = s0 * sc0 + e0;
            s1 = s1 * sc1 + e1;

            const uint4 w0 = vq[bg0 + (i << 7)];
            const uint4 w1 = vq[bg1 + (i << 7)];
            p[0]  = p[0]  * sc0 + e0 * bflo(w0.x); p[1]  = p[1]  * sc0 + e0 * bfhi(w0.x);
            p[2]  = p[2]  * sc0 + e0 * bflo(w0.y); p[3]  = p[3]  * sc0 + e0 * bfhi(w0.y);
            p[4]  = p[4]  * sc0 + e0 * bflo(w0.z); p[5]  = p[5]  * sc0 + e0 * bfhi(w0.z);
            p[6]  = p[6]  * sc0 + e0 * bflo(w0.w); p[7]  = p[7]  * sc0 + e0 * bfhi(w0.w);
            p[8]  = p[8]  * sc1 + e1 * bflo(w1.x); p[9]  = p[9]  * sc1 + e1 * bfhi(w1.x);
            p[10] = p[10] * sc1 + e1 * bflo(w1.y); p[11] = p[11] * sc1 + e1 * bfhi(w1.y);
            p[12] = p[12] * sc1 + e1 * bflo(w1.z); p[13] = p[13] * sc1 + e1 * bfhi(w1.z);
            p[14] = p[14] * sc1 + e1 * bflo(w1.w); p[15] = p[15] * sc1 + e1 * bfhi(w1.w);
        }

        // ---- combine per-lane online states: global max/sum, rescale local p ----
        const float ml0 = m0, ml1 = m1;           // save local maxes
        #pragma unroll
        for (int s = 32; s; s >>= 1) {
            const float om0 = __shfl_xor(m0, s, 64), os0 = __shfl_xor(s0, s, 64);
            const float om1 = __shfl_xor(m1, s, 64), os1 = __shfl_xor(s1, s, 64);
            const float nm0 = fmaxf(m0, om0),        nm1 = fmaxf(m1, om1);
            s0 = s0 * __expf(m0 - nm0) + os0 * __expf(om0 - nm0);
            s1 = s1 * __expf(m1 - nm1) + os1 * __expf(om1 - nm1);
            m0 = nm0; m1 = nm1;
        }
        {
            const float r0 = __expf(ml0 - m0);    // exp(local - global) in [0,1]
            const float r1 = __expf(ml1 - m1);
            #pragma unroll
            for (int k = 0; k < 8; ++k)  p[k] *= r0;
            #pragma unroll
            for (int k = 8; k < 16; ++k) p[k] *= r1;
        }

        // ---- split butterfly reduce: lane ends owning element e = lane>>2 ----
        {
            const bool h5 = (lane & 32) != 0;
            #pragma unroll
            for (int k = 0; k < 8; ++k) {
                const float snd = h5 ? p[k] : p[k + 8];
                const float kp  = h5 ? p[k + 8] : p[k];
                p[k] = kp + __shfl_xor(snd, 32, 64);
            }
            const bool h4 = (lane & 16) != 0;
            #pragma unroll
            for (int k = 0; k < 4; ++k) {
                const float snd = h4 ? p[k] : p[k + 4];
                const float kp  = h4 ? p[k + 4] : p[k];
                p[k] = kp + __shfl_xor(snd, 16, 64);
            }
            const bool h3 = (lane & 8) != 0;
            #pragma unroll
            for (int k = 0; k < 2; ++k) {
                const float snd = h3 ? p[k] : p[k + 2];
                const float kp  = h3 ? p[k + 2] : p[k];
                p[k] = kp + __shfl_xor(snd, 8, 64);
            }
            const bool h2 = (lane & 4) != 0;
            {
                const float snd = h2 ? p[0] : p[1];
                const float kp  = h2 ? p[1] : p[0];
                p[0] = kp + __shfl_xor(snd, 4, 64);
            }
            p[0] += __shfl_xor(p[0], 2, 64);
            p[0] += __shfl_xor(p[0], 1, 64);
        }

        const float inv0 = 1.0f / s0, inv1 = 1.0f / s1;
        const float pn = p[0] * (lane >= 32 ? inv1 : inv0);   // attn[c] lives at lane 4*c

        // ---- att[j] = exp(-(attn . Wo[:,j] + Bo[j])) on all lanes (j = lane&15) ----
        float attv;
        {
            const int j = lane & 15;
            float acc = Bo[j];
            #pragma unroll
            for (int c = 0; c < 16; ++c)
                acc += __shfl(pn, 4 * c, 64) * Wo[c * 16 + j];
            attv = __expf(-acc);
        }

        // ---- layer 1 ----
        float a1;
        {
            float acc = B1[lane];
            acc += c1.x * W1[0 * 64 + lane] + c1.y * W1[1 * 64 + lane]
                 + c1.z * W1[2 * 64 + lane] + c1.w * W1[3 * 64 + lane];
            acc += c2.x * W1[4 * 64 + lane] + c2.y * W1[5 * 64 + lane]
                 + c2.z * W1[6 * 64 + lane] + c2.w * W1[7 * 64 + lane];
            #pragma unroll
            for (int c = 0; c < 16; ++c)
                acc += __shfl(attv, c, 64) * W1[(8 + c) * 64 + lane];
            a1 = ftanh(acc);
        }

        // ---- layer 2 ----
        float a2;
        {
            float acc = B2[lane];
            #pragma unroll
            for (int c = 0; c < 64; ++c)
                acc += __shfl(a1, c, 64) * W2[c * 64 + lane];
            a2 = ftanh(acc);
        }

        // ---- layer 3 ----
        {
            const int j = lane & 31;
            float acc = Bt[j];
            #pragma unroll
            for (int c = 0; c < 64; ++c)
                acc += __shfl(a2, c, 64) * Wt[c * 32 + j];
            if (lane < 32) out[(size_t)n * 32 + lane] = ftanh(acc);
        }
    }
}

extern "C" void kernel_launch(void* const* d_in, const int* in_sizes, int n_in,
                              void* d_out, int out_size, void* d_ws, size_t ws_size,
                              hipStream_t stream) {
    (void)in_sizes; (void)n_in; (void)out_size; (void)d_ws; (void)ws_size;
    attn_mlp_fused<<<1024, 256, 0, stream>>>(
        (const float*)d_in[0],  (const float*)d_in[1],
        (const float*)d_in[2],  (const float*)d_in[3],
        d_in[4],
        (const float*)d_in[5],  (const float*)d_in[6],
        (const float*)d_in[7],  (const float*)d_in[8],
        (const float*)d_in[9],  (const float*)d_in[10],
        (const float*)d_in[11], (const float*)d_in[12],
        (const float*)d_in[13], (const float*)d_in[14],
        (const float*)d_in[15], (const float*)d_in[16],
        (const float*)d_in[17], (const float*)d_in[18],
        (float*)d_out);
}